// Round 2
// baseline (42170.038 us; speedup 1.0000x reference)
//
#include <hip/hip_runtime.h>
#include <stdint.h>

// LSTM_29042568856007: B=64, T=4096, D=256, H=256.
// Round 2: split each batch across 4 WGs (256 WGs ~= 256 CUs). Each WG owns
// 64 hidden units (256 gate rows), streams 256 KB/step of bf16 weights from
// L2 (vs 1 MB in round 1 -> per-CU L2 BW was the bottleneck at ~60 B/cyc).
// Partner WGs exchange h each step via agent-scope atomics + flag counter.

#define LSTM_B 64
#define LSTM_T 4096
#define LSTM_D 256
#define LSTM_H 256

// ws layout:
//   Wp    : uint4[4][64][256]            @ 0        (1 MiB)  packed bf16 pairs
//   hbuf  : float[2][64][256]            @ 1 MiB    (128 KiB) h exchange (double buf)
//   flags : uint[64*32]                  @ 1 MiB+128K (8 KiB) per-batch step counters
#define WS_WP_BYTES   (1u << 20)
#define WS_HBUF_OFF   (WS_WP_BYTES)
#define WS_FLAGS_OFF  (WS_WP_BYTES + 131072u)

static __device__ __forceinline__ uint32_t f32_to_bf16_rne(float f) {
    uint32_t u = __float_as_uint(f);
    uint32_t rounding = 0x7fffu + ((u >> 16) & 1u);
    return (u + rounding) >> 16;
}

// Pack weights into Wp[((j*64 + k4)*256 + rp)] as uint4; rp encodes (g = rp>>6,
// u = rp&63) -> gate row r = 256*g + 64*j + u. k4<32: W_ih k=8*k4.. ; k4>=32:
// W_hh k=8*(k4-32).. . Also zero the flags.
__global__ __launch_bounds__(256) void prep_weights(
    const float* __restrict__ W_ih, const float* __restrict__ W_hh,
    uint32_t* __restrict__ Wp, uint32_t* __restrict__ flags)
{
    int idx = blockIdx.x * blockDim.x + threadIdx.x;  // u32 index in [0, 262144)
    if (idx < 64 * 32) flags[idx] = 0;
    if (idx >= 4 * 64 * 256 * 4) return;
    int e  = idx & 3;
    int rp = (idx >> 2) & 255;
    int k4 = (idx >> 10) & 63;
    int j  = idx >> 16;
    int g  = rp >> 6, u = rp & 63;
    int r  = 256 * g + 64 * j + u;
    int k  = 8 * (k4 & 31) + 2 * e;
    const float* W = (k4 < 32) ? W_ih : W_hh;
    float f0 = W[r * 256 + k];
    float f1 = W[r * 256 + k + 1];
    Wp[idx] = f32_to_bf16_rne(f0) | (f32_to_bf16_rne(f1) << 16);
}

static __device__ __forceinline__ float sigmoidf_(float x) {
    return 1.0f / (1.0f + __expf(-x));
}
static __device__ __forceinline__ float tanhf_(float x) {
    float ax = fabsf(x);
    float e  = __expf(-2.0f * ax);
    float t  = (1.0f - e) / (1.0f + e);
    return copysignf(t, x);
}

static __device__ __forceinline__ float agent_load_f32(const float* p) {
    return __hip_atomic_load(p, __ATOMIC_RELAXED, __HIP_MEMORY_SCOPE_AGENT);
}
static __device__ __forceinline__ void agent_store_f32(float* p, float v) {
    __hip_atomic_store(p, v, __ATOMIC_RELAXED, __HIP_MEMORY_SCOPE_AGENT);
}
static __device__ __forceinline__ uint32_t agent_load_u32(const uint32_t* p) {
    return __hip_atomic_load(p, __ATOMIC_RELAXED, __HIP_MEMORY_SCOPE_AGENT);
}

// 8 bf16 weights (uint4 w) * 8 fp32 activations, two accumulators for ILP
#define UNPACK_FMA8(w, a0, a1)                                         \
    acc0 = fmaf(__uint_as_float((w).x << 16),          (a0).x, acc0);  \
    acc1 = fmaf(__uint_as_float((w).x & 0xffff0000u),  (a0).y, acc1);  \
    acc0 = fmaf(__uint_as_float((w).y << 16),          (a0).z, acc0);  \
    acc1 = fmaf(__uint_as_float((w).y & 0xffff0000u),  (a0).w, acc1);  \
    acc0 = fmaf(__uint_as_float((w).z << 16),          (a1).x, acc0);  \
    acc1 = fmaf(__uint_as_float((w).z & 0xffff0000u),  (a1).y, acc1);  \
    acc0 = fmaf(__uint_as_float((w).w << 16),          (a1).z, acc0);  \
    acc1 = fmaf(__uint_as_float((w).w & 0xffff0000u),  (a1).w, acc1);

__global__ __launch_bounds__(512, 2) void lstm_split4(
    const float* __restrict__ xs,     // [B, T, D]
    const float* __restrict__ bias_g, // [4H]
    const uint4* __restrict__ Wp,
    float* __restrict__ hbuf,         // [2][64][256]
    uint32_t* __restrict__ flags,     // [64*32]
    float* __restrict__ out)          // h[B,H] then c[B,H]
{
    __shared__ __align__(16) float x_s[LSTM_D];
    __shared__ __align__(16) float h_s[LSTM_H];
    __shared__ __align__(16) float p_s[512];

    const int tid = threadIdx.x;
    const int b   = blockIdx.x & 63;   // batch; partners are 64 apart -> same XCD (likely)
    const int j   = blockIdx.x >> 6;   // quarter: hidden units [64j, 64j+64)

    const int rr = tid & 255;          // row-in-slice: g = rr>>6, u = rr&63
    const int kh = tid >> 8;           // k-half: 0 = x part (k4 0..31), 1 = h part

    const float bias0 = (kh == 0) ? bias_g[256 * (rr >> 6) + 64 * j + (rr & 63)] : 0.0f;

    const float* xrow = xs + (size_t)b * LSTM_T * LSTM_D;
    const uint4* Wr   = Wp + (((j * 64 + kh * 32) << 8) + rr);
    uint32_t* flag    = flags + b * 32;

    if (tid < LSTM_H) h_s[tid] = 0.0f;
    float c = 0.0f, hlast = 0.0f;
    float xn = (tid < 256) ? xrow[tid] : 0.0f;  // prefetch x_0

    for (int t = 0; t < LSTM_T; ++t) {
        // ---- Phase A: wait for h_t, gather foreign h values ----
        if (t > 0) {
            if (tid == 0) {
                const uint32_t target = 4u * (uint32_t)t;
                while (agent_load_u32(flag) < target) __builtin_amdgcn_s_sleep(2);
                __threadfence();  // acquire: order flag read before hbuf reads
            }
            __syncthreads();  // bar A
            if (tid < 192) {
                int m = tid + ((tid >= 64 * j) ? 64 : 0);  // skip own 64-block
                h_s[m] = agent_load_f32(&hbuf[(t & 1) * 16384 + b * 256 + m]);
            }
        }
        if (tid < 256) x_s[tid] = xn;
        __syncthreads();      // bar B: x_s, h_s ready

        // prefetch next x during the dot loop
        if (tid < 256 && t + 1 < LSTM_T) xn = xrow[(t + 1) * LSTM_D + tid];

        // ---- Phase B: half-row dot products (256 MACs / thread) ----
        float acc0 = bias0, acc1 = 0.0f;
        const float4* act4 = kh ? (const float4*)h_s : (const float4*)x_s;
        #pragma unroll 8
        for (int kk = 0; kk < 32; ++kk) {
            uint4  w  = Wr[kk << 8];
            float4 a0 = act4[2 * kk];
            float4 a1 = act4[2 * kk + 1];
            UNPACK_FMA8(w, a0, a1)
        }
        p_s[tid] = acc0 + acc1;
        __syncthreads();      // bar C: partials ready

        // ---- Phase C: gate nonlinearity + state update (wave 0 only) ----
        if (tid < 64) {
            int u = tid;
            float gi = p_s[u]       + p_s[u + 256];
            float gf = p_s[u + 64]  + p_s[u + 320];
            float gg = p_s[u + 128] + p_s[u + 384];
            float go = p_s[u + 192] + p_s[u + 448];
            c = sigmoidf_(gf) * c + sigmoidf_(gi) * tanhf_(gg);
            float h = sigmoidf_(go) * tanhf_(c);
            hlast = h;
            int m = 64 * j + u;
            h_s[m] = h;  // own slice for next step's kh=1 dot
            agent_store_f32(&hbuf[((t + 1) & 1) * 16384 + b * 256 + m], h);
        }
        if (tid == 0) {
            __threadfence();            // release: drain wave 0's h stores
            atomicAdd(flag, 1u);        // device-scope by default
        }
        // next iteration's bar A/B orders everything else
    }

    if (tid < 64) {
        int m = 64 * j + tid;
        out[b * LSTM_H + m]                     = hlast;  // h_T
        out[LSTM_B * LSTM_H + b * LSTM_H + m]   = c;      // c_T
    }
}

extern "C" void kernel_launch(void* const* d_in, const int* in_sizes, int n_in,
                              void* d_out, int out_size, void* d_ws, size_t ws_size,
                              hipStream_t stream) {
    const float* xs   = (const float*)d_in[0];  // [64,4096,256]
    const float* W_ih = (const float*)d_in[1];  // [1024,256]
    const float* W_hh = (const float*)d_in[2];  // [1024,256]
    const float* b    = (const float*)d_in[3];  // [1024]
    float* out = (float*)d_out;

    char* ws = (char*)d_ws;
    uint32_t* Wp    = (uint32_t*)ws;
    float*    hbuf  = (float*)(ws + WS_HBUF_OFF);
    uint32_t* flags = (uint32_t*)(ws + WS_FLAGS_OFF);

    prep_weights<<<1024, 256, 0, stream>>>(W_ih, W_hh, Wp, flags);
    lstm_split4<<<256, 512, 0, stream>>>(xs, b, (const uint4*)Wp, hbuf, flags, out);
}